// Round 1
// baseline (329.088 us; speedup 1.0000x reference)
//
#include <hip/hip_runtime.h>
#include <math.h>

namespace {
constexpr int Bn = 8, Cn = 256, Hn = 96, Wn = 128;
constexpr int HWn = Hn * Wn;          // 12288
constexpr int CHWn = Cn * HWn;
constexpr int Kn = 81;
constexpr int TW = 32, TH = 8;        // tile per block
constexpr int HR = TH + 8;            // 16 halo rows
constexpr int HC = TW + 8;            // 40 halo cols
constexpr int HCP = 44;               // padded LDS row stride (floats)
constexpr int CC = 8;                 // channels per LDS chunk
constexpr int NTHREADS = 8 * 3 * 8;   // 192 = tx(8) * g(3) * ty(8)
}

__global__ __launch_bounds__(NTHREADS)
void corr81_kernel(const float* __restrict__ fa,
                   const float* __restrict__ fb,
                   float* __restrict__ out) {
  __shared__ __align__(16) float lfb[CC][HR][HCP];
  __shared__ float ssb[HR * HC];   // fb per-pixel sum of squares -> rnorm

  const int tx = threadIdx.x;      // 0..7  column group (4 px each)
  const int g  = threadIdx.y;      // 0..2  dy group (3 dy rows each)
  const int ty = threadIdx.z;      // 0..7  row in tile
  const int tid = tx + 8 * g + 24 * ty;

  // XCD swizzle: blocks are dispatched round-robin over 8 XCDs by id%8.
  // Map so XCD k gets the 48 tiles of batch image k -> fb halo reuse in L2.
  const int flat = blockIdx.x;
  const int o = (flat & 7) * 48 + (flat >> 3);
  const int b  = o / 48;
  const int r  = o % 48;
  const int h0 = (r >> 2) * TH;
  const int w0 = (r & 3) * TW;
  const int wb = w0 + 4 * tx;

  for (int i = tid; i < HR * HC; i += NTHREADS) ssb[i] = 0.0f;

  float acc[27][4];
  #pragma unroll
  for (int k = 0; k < 27; ++k) {
    #pragma unroll
    for (int j = 0; j < 4; ++j) acc[k][j] = 0.0f;
  }
  float ssa[4] = {0.f, 0.f, 0.f, 0.f};

  const float* faP = fa + (size_t)b * CHWn + (h0 + ty) * Wn + wb;

  // staging assignments: 640 halo px over 192 threads, 4 rounds
  int   s_hr[4], s_hc[4];
  bool  s_on[4], s_ok[4];
  const float* s_ptr[4];
  #pragma unroll
  for (int i = 0; i < 4; ++i) {
    int px = tid + NTHREADS * i;
    s_on[i] = (px < HR * HC);
    int hr = px / HC, hc = px - hr * HC;
    s_hr[i] = hr; s_hc[i] = hc;
    int gh = h0 - 4 + hr, gw = w0 - 4 + hc;
    s_ok[i] = s_on[i] && gh >= 0 && gh < Hn && gw >= 0 && gw < Wn;
    s_ptr[i] = fb + (size_t)b * CHWn + (size_t)gh * Wn + gw;
  }
  __syncthreads();

  for (int c0 = 0; c0 < Cn; c0 += CC) {
    // ---- stage fb chunk into LDS, accumulate fb sumsq (owner-exclusive) ----
    #pragma unroll
    for (int i = 0; i < 4; ++i) {
      if (s_on[i]) {
        float ss = 0.f;
        if (s_ok[i]) {
          const float* p = s_ptr[i] + (size_t)c0 * HWn;
          #pragma unroll
          for (int cc = 0; cc < CC; ++cc) {
            float v = p[(size_t)cc * HWn];
            lfb[cc][s_hr[i]][s_hc[i]] = v;
            ss += v * v;
          }
        } else {
          #pragma unroll
          for (int cc = 0; cc < CC; ++cc) lfb[cc][s_hr[i]][s_hc[i]] = 0.f;
        }
        ssb[s_hr[i] * HC + s_hc[i]] += ss;
      }
    }
    // fa prefetch (independent of the barrier)
    float4 areg[CC];
    #pragma unroll
    for (int cc = 0; cc < CC; ++cc)
      areg[cc] = *(const float4*)(faP + (size_t)(c0 + cc) * HWn);
    __syncthreads();

    // ---- compute: 27 shifts x 4 px per thread ----
    #pragma unroll
    for (int cc = 0; cc < CC; ++cc) {
      const float a0 = areg[cc].x, a1 = areg[cc].y, a2 = areg[cc].z, a3 = areg[cc].w;
      ssa[0] += a0 * a0; ssa[1] += a1 * a1; ssa[2] += a2 * a2; ssa[3] += a3 * a3;
      #pragma unroll
      for (int ro = 0; ro < 3; ++ro) {
        const float* rowp = &lfb[cc][ty + 3 * g + ro][4 * tx];
        const float4 wa = *(const float4*)(rowp);
        const float4 wv = *(const float4*)(rowp + 4);
        const float4 wc = *(const float4*)(rowp + 8);
        const float win[12] = {wa.x, wa.y, wa.z, wa.w,
                               wv.x, wv.y, wv.z, wv.w,
                               wc.x, wc.y, wc.z, wc.w};
        #pragma unroll
        for (int dx = 0; dx < 9; ++dx) {
          acc[ro * 9 + dx][0] += a0 * win[dx + 0];
          acc[ro * 9 + dx][1] += a1 * win[dx + 1];
          acc[ro * 9 + dx][2] += a2 * win[dx + 2];
          acc[ro * 9 + dx][3] += a3 * win[dx + 3];
        }
      }
    }
    __syncthreads();
  }

  // ---- epilogue: turn sumsq into 1/max(norm,eps), then scale + store ----
  for (int i = tid; i < HR * HC; i += NTHREADS) {
    ssb[i] = 1.0f / fmaxf(sqrtf(ssb[i]), 1e-12f);
  }
  float rna[4];
  #pragma unroll
  for (int j = 0; j < 4; ++j) rna[j] = 1.0f / fmaxf(sqrtf(ssa[j]), 1e-12f);
  __syncthreads();

  float* outP = out + (size_t)b * (Kn * HWn) + (h0 + ty) * Wn + wb;
  #pragma unroll
  for (int ro = 0; ro < 3; ++ro) {
    const int dy = 3 * g + ro;
    const int rr = ty + dy;           // halo row of fb pixel
    #pragma unroll
    for (int dx = 0; dx < 9; ++dx) {
      const int k = dy * 9 + dx;
      float4 v;
      v.x = acc[ro * 9 + dx][0] * rna[0] * ssb[rr * HC + 4 * tx + dx + 0];
      v.y = acc[ro * 9 + dx][1] * rna[1] * ssb[rr * HC + 4 * tx + dx + 1];
      v.z = acc[ro * 9 + dx][2] * rna[2] * ssb[rr * HC + 4 * tx + dx + 2];
      v.w = acc[ro * 9 + dx][3] * rna[3] * ssb[rr * HC + 4 * tx + dx + 3];
      *(float4*)(outP + (size_t)k * HWn) = v;
    }
  }
}

extern "C" void kernel_launch(void* const* d_in, const int* in_sizes, int n_in,
                              void* d_out, int out_size, void* d_ws, size_t ws_size,
                              hipStream_t stream) {
  const float* fa = (const float*)d_in[0];
  const float* fb = (const float*)d_in[1];
  float* outp = (float*)d_out;
  dim3 grid(Bn * 48);    // 384 blocks: 8 b * 12 h-tiles * 4 w-tiles
  dim3 block(8, 3, 8);   // 192 threads
  hipLaunchKernelGGL(corr81_kernel, grid, block, 0, stream, fa, fb, outp);
}

// Round 2
// 275.710 us; speedup vs baseline: 1.1936x; 1.1936x over previous
//
#include <hip/hip_runtime.h>
#include <math.h>

namespace {
constexpr int Bn = 8, Cn = 256, Hn = 96, Wn = 128;
constexpr int HWn = Hn * Wn;          // 12288
constexpr int CHWn = Cn * HWn;
constexpr int Kn = 81;
constexpr int TW = 32, TH = 6;        // tile per block
constexpr int HR = TH + 8;            // 14 halo rows
constexpr int HC = TW + 8;            // 40 halo cols
constexpr int HCP = 44;               // padded LDS row stride (floats)
constexpr int CC = 8;                 // channels per LDS chunk
constexpr int NTHREADS = 8 * 9 * 6;   // 432 = tx(8) * g(9) * ty(6)
constexpr int HALO = HR * HC;         // 560
}

__global__ __launch_bounds__(NTHREADS, 4)
void corr81_kernel(const float* __restrict__ fa,
                   const float* __restrict__ fb,
                   float* __restrict__ out) {
  __shared__ __align__(16) float lfb[CC][HR][HCP];
  __shared__ float ssb[HALO];      // fb per-pixel sum of squares -> rnorm

  const int tx = threadIdx.x;      // 0..8  column group (4 px each)
  const int g  = threadIdx.y;      // 0..8  == dy
  const int ty = threadIdx.z;      // 0..5  row in tile
  const int tid = tx + 8 * g + 72 * ty;

  // XCD swizzle: id%8 -> XCD; give each XCD one batch image's 64 tiles.
  const int flat = blockIdx.x;
  const int o = (flat & 7) * 64 + (flat >> 3);
  const int b  = o >> 6;
  const int r  = o & 63;
  const int h0 = (r >> 2) * TH;
  const int w0 = (r & 3) * TW;
  const int wb = w0 + 4 * tx;

  for (int i = tid; i < HALO; i += NTHREADS) ssb[i] = 0.0f;

  float acc[9][4];
  #pragma unroll
  for (int k = 0; k < 9; ++k) {
    #pragma unroll
    for (int j = 0; j < 4; ++j) acc[k][j] = 0.0f;
  }
  float ssa[4] = {0.f, 0.f, 0.f, 0.f};

  const float* faP = fa + (size_t)b * CHWn + (h0 + ty) * Wn + wb;

  // staging assignments: 560 halo px over 432 threads, 2 rounds
  int   s_hr[2], s_hc[2];
  bool  s_on[2], s_ok[2];
  const float* s_ptr[2];
  #pragma unroll
  for (int i = 0; i < 2; ++i) {
    int px = tid + NTHREADS * i;
    s_on[i] = (px < HALO);
    int hr = px / HC, hc = px - hr * HC;
    s_hr[i] = hr; s_hc[i] = hc;
    int gh = h0 - 4 + hr, gw = w0 - 4 + hc;
    s_ok[i] = s_on[i] && gh >= 0 && gh < Hn && gw >= 0 && gw < Wn;
    s_ptr[i] = fb + (size_t)b * CHWn + (size_t)gh * Wn + gw;
  }
  __syncthreads();

  for (int c0 = 0; c0 < Cn; c0 += CC) {
    // ---- stage fb chunk into LDS, accumulate fb sumsq (owner-exclusive) ----
    #pragma unroll
    for (int i = 0; i < 2; ++i) {
      if (s_on[i]) {
        float ss = 0.f;
        if (s_ok[i]) {
          const float* p = s_ptr[i] + (size_t)c0 * HWn;
          #pragma unroll
          for (int cc = 0; cc < CC; ++cc) {
            float v = p[(size_t)cc * HWn];
            lfb[cc][s_hr[i]][s_hc[i]] = v;
            ss += v * v;
          }
        } else {
          #pragma unroll
          for (int cc = 0; cc < CC; ++cc) lfb[cc][s_hr[i]][s_hc[i]] = 0.f;
        }
        ssb[s_hr[i] * HC + s_hc[i]] += ss;
      }
    }
    // fa prefetch (independent of the barrier; L1-served across g groups)
    float4 areg[CC];
    #pragma unroll
    for (int cc = 0; cc < CC; ++cc)
      areg[cc] = *(const float4*)(faP + (size_t)(c0 + cc) * HWn);
    __syncthreads();

    // ---- compute: one dy (=g), 9 dx shifts x 4 px per thread ----
    #pragma unroll
    for (int cc = 0; cc < CC; ++cc) {
      const float a0 = areg[cc].x, a1 = areg[cc].y, a2 = areg[cc].z, a3 = areg[cc].w;
      ssa[0] += a0 * a0; ssa[1] += a1 * a1; ssa[2] += a2 * a2; ssa[3] += a3 * a3;
      const float* rowp = &lfb[cc][ty + g][4 * tx];
      const float4 wa = *(const float4*)(rowp);
      const float4 wv = *(const float4*)(rowp + 4);
      const float4 wc = *(const float4*)(rowp + 8);
      const float win[12] = {wa.x, wa.y, wa.z, wa.w,
                             wv.x, wv.y, wv.z, wv.w,
                             wc.x, wc.y, wc.z, wc.w};
      #pragma unroll
      for (int dx = 0; dx < 9; ++dx) {
        acc[dx][0] += a0 * win[dx + 0];
        acc[dx][1] += a1 * win[dx + 1];
        acc[dx][2] += a2 * win[dx + 2];
        acc[dx][3] += a3 * win[dx + 3];
      }
    }
    __syncthreads();
  }

  // ---- epilogue: turn sumsq into 1/max(norm,eps), then scale + store ----
  for (int i = tid; i < HALO; i += NTHREADS) {
    ssb[i] = 1.0f / fmaxf(sqrtf(ssb[i]), 1e-12f);
  }
  float rna[4];
  #pragma unroll
  for (int j = 0; j < 4; ++j) rna[j] = 1.0f / fmaxf(sqrtf(ssa[j]), 1e-12f);
  __syncthreads();

  float* outP = out + (size_t)b * (Kn * HWn) + (h0 + ty) * Wn + wb;
  const int rr = ty + g;             // halo row of fb pixel for dy=g
  #pragma unroll
  for (int dx = 0; dx < 9; ++dx) {
    const int k = g * 9 + dx;
    float4 v;
    v.x = acc[dx][0] * rna[0] * ssb[rr * HC + 4 * tx + dx + 0];
    v.y = acc[dx][1] * rna[1] * ssb[rr * HC + 4 * tx + dx + 1];
    v.z = acc[dx][2] * rna[2] * ssb[rr * HC + 4 * tx + dx + 2];
    v.w = acc[dx][3] * rna[3] * ssb[rr * HC + 4 * tx + dx + 3];
    *(float4*)(outP + (size_t)k * HWn) = v;
  }
}

extern "C" void kernel_launch(void* const* d_in, const int* in_sizes, int n_in,
                              void* d_out, int out_size, void* d_ws, size_t ws_size,
                              hipStream_t stream) {
  const float* fa = (const float*)d_in[0];
  const float* fb = (const float*)d_in[1];
  float* outp = (float*)d_out;
  dim3 grid(512);        // 8 b * 16 h-tiles * 4 w-tiles -> exactly 2 blocks/CU
  dim3 block(8, 9, 6);   // 432 threads
  hipLaunchKernelGGL(corr81_kernel, grid, block, 0, stream, fa, fb, outp);
}